// Round 23
// baseline (195.621 us; speedup 1.0000x reference)
//
#include <hip/hip_runtime.h>
#include <hip/hip_bf16.h>
#include <math.h>

// ---------------------------------------------------------------------------
// LanguageModel_66477503807731: top-1 MoE FFN + tridiagonal Green's-function
// spectral features. B=4,N=4096,D=512,E=4,F=2048. Output fp32.
// R23: gemm1 -> BK=32 FULLY double-buffered at 48KB (the untried matrix cell
// satisfying BOTH the occupancy law (<=48KB -> 2-3 blk/CU) AND the R20
// pipelined schedule whose per-block rate was 1.65x better):
//   LDS A[2][256x32] + B[2][128x32] = 48KB; 16 K-steps; ONE barrier/step:
//   { vmcnt(0)+s_barrier (stage(kt) landed; flight time = prior compute);
//     issue stage(kt+1)->buf^1 (3 gloads/thr); 8 ds_read + 16 MFMA }.
//   64B LDS rows: frag reads consume all 4 slots/row -> banks perfectly
//   balanced, NO swizzle needed (unlike 128B rows). K order unchanged ->
//   absmax bit-identical. gemm2 kept at proven R16 config (hedge).
// Rest identical to R22 (194.7us): direct perm-gather A, merged prep+trans,
// ballot routing, prefetched scan, fast_gelu.
// ---------------------------------------------------------------------------

typedef __bf16 bf16x8 __attribute__((ext_vector_type(8)));
typedef float  f32x4  __attribute__((ext_vector_type(4)));
typedef __attribute__((address_space(3))) __bf16 lbf16;

#define B_   4
#define N_   4096
#define D_   512
#define E_   4
#define F_   2048
#define T_   (B_*N_)        // 16384 tokens
#define CAP_ T_
#define R256 68             // max 256-row tiles: 16384/256 + 4
#define PADROWS (R256*256)  // 17408

#define LGKM_BARRIER() asm volatile("s_waitcnt lgkmcnt(0)\n\ts_barrier" ::: "memory")
#define VM0_BARRIER()  asm volatile("s_waitcnt vmcnt(0)\n\ts_barrier" ::: "memory")

__device__ __forceinline__ void gload_lds16(const __bf16* g, lbf16* l) {
    __builtin_amdgcn_global_load_lds(
        (__attribute__((address_space(1))) void*)(void*)g,
        (__attribute__((address_space(3))) void*)l, 16, 0, 0);
}

__device__ __forceinline__ float fast_gelu(float x) {
    float u = 1.5957691216f * fmaf(0.044715f * x, x * x, x);
    return x / (1.0f + __expf(-u));
}

// Load 8 consecutive float2 (16B-aligned base) as 4x float4.
__device__ __forceinline__ void load8f2(const float2* p, float2* dst) {
    const float4* q = (const float4*)p;
    #pragma unroll
    for (int i = 0; i < 4; ++i) {
        float4 t = q[i];
        dst[2*i]   = make_float2(t.x, t.y);
        dst[2*i+1] = make_float2(t.z, t.w);
    }
}

// One BK=64 MFMA phase for a 64x64 wave tile (gemm2): 16 ds_read + 32 MFMA.
__device__ __forceinline__ void mfma_tile(const char* Ab, const char* Bb,
                                          int cs0, int cs1, f32x4 acc[4][4]) {
    #pragma unroll
    for (int ks = 0; ks < 2; ++ks) {
        int cs = ks ? cs1 : cs0;
        bf16x8 af[4], bfr[4];
        #pragma unroll
        for (int m = 0; m < 4; ++m)
            af[m] = *(const bf16x8*)(Ab + m * 2048 + cs);
        #pragma unroll
        for (int n = 0; n < 4; ++n)
            bfr[n] = *(const bf16x8*)(Bb + n * 2048 + cs);
        #pragma unroll
        for (int m = 0; m < 4; ++m)
            #pragma unroll
            for (int n = 0; n < 4; ++n)
                acc[m][n] = __builtin_amdgcn_mfma_f32_16x16x32_bf16(af[m], bfr[n], acc[m][n], 0, 0, 0);
    }
}

// One BK=32 step for gemm1 (64B rows, no swizzle): 8 ds_read + 16 MFMA.
__device__ __forceinline__ void mfma_step32(const char* Ab, const char* Bb,
                                            int gl16, f32x4 acc[4][4]) {
    bf16x8 af[4], bfr[4];
    #pragma unroll
    for (int m = 0; m < 4; ++m)
        af[m] = *(const bf16x8*)(Ab + m * 1024 + gl16);
    #pragma unroll
    for (int n = 0; n < 4; ++n)
        bfr[n] = *(const bf16x8*)(Bb + n * 1024 + gl16);
    #pragma unroll
    for (int m = 0; m < 4; ++m)
        #pragma unroll
        for (int n = 0; n < 4; ++n)
            acc[m][n] = __builtin_amdgcn_mfma_f32_16x16x32_bf16(af[m], bfr[n], acc[m][n], 0, 0, 0);
}

// Fallback-only static scratch (used iff ws_size too small; ws observed 256MB).
__device__ alignas(256) __bf16 s_w1t[(size_t)E_*F_*D_];
__device__ alignas(256) __bf16 s_w2t[(size_t)E_*D_*F_];
__device__ alignas(256) __bf16 s_xl[(size_t)T_*D_];
__device__ alignas(256) __bf16 s_H[(size_t)PADROWS*F_];
__device__ alignas(256) float2 s_d[T_];
__device__ alignas(256) float2 s_feats[T_];
__device__ alignas(256) float2 s_L[T_];
__device__ alignas(256) float2 s_U[T_];
__device__ alignas(256) int    s_perm[E_*CAP_];
__device__ alignas(256) int    s_cnt[E_];
__device__ alignas(256) int    s_tpre[8];
__device__ alignas(256) int    s_eid[T_];

__device__ inline float dot8(float4 a, float4 b, float4 c, float4 d) {
    float s =      a.x * c.x;
    s = fmaf(a.y, c.y, s); s = fmaf(a.z, c.z, s); s = fmaf(a.w, c.w, s);
    s = fmaf(b.x, d.x, s); s = fmaf(b.y, d.y, s); s = fmaf(b.z, d.z, s);
    s = fmaf(b.w, d.w, s);
    return s;
}

__device__ inline float wave_sum(float s) {
    #pragma unroll
    for (int off = 32; off > 0; off >>= 1) s += __shfl_xor(s, off);
    return s;
}

// ---------------------------------------------------------------------------
// Merged: weight transposes (blocks [0,8192)) + prep (blocks [8192,12288)).
// Prep also writes xlin[token][512] bf16 (token-linear activation).
// ---------------------------------------------------------------------------
__global__ __launch_bounds__(256) void prep_trans_kernel(
        const float* __restrict__ w1, const float* __restrict__ w2,
        __bf16* __restrict__ w1t, __bf16* __restrict__ w2t,
        const float* __restrict__ x,
        const float* __restrict__ vw, const float* __restrict__ vb,
        const float* __restrict__ gamma, const float* __restrict__ epsp,
        const float* __restrict__ gw, const float* __restrict__ gb,
        float2* __restrict__ dbuf, int* __restrict__ eid,
        __bf16* __restrict__ xlin) {
    __shared__ alignas(16) float tile[32][33];
    int idx = blockIdx.x;
    int tid = threadIdx.x;
    if (idx < 8192) {
        int which = idx >> 12;            // 0: w1, 1: w2
        int r = idx & 4095;
        int e = r >> 10;
        int t = r & 1023;
        int R, C, c0, r0;
        const float* s;
        __bf16* d;
        if (which == 0) { R = D_; C = F_; c0 = (t & 63) * 32; r0 = (t >> 6) * 32;
                          s = w1 + (size_t)e * R * C; d = w1t + (size_t)e * R * C; }
        else            { R = F_; C = D_; c0 = (t & 15) * 32; r0 = (t >> 4) * 32;
                          s = w2 + (size_t)e * R * C; d = w2t + (size_t)e * R * C; }
        int tx = tid & 31, ty = tid >> 5;
        #pragma unroll
        for (int i = 0; i < 4; ++i)
            tile[ty + i*8][tx] = s[(size_t)(r0 + ty + i*8) * C + c0 + tx];
        __syncthreads();
        #pragma unroll
        for (int i = 0; i < 4; ++i)
            d[(size_t)(c0 + ty + i*8) * R + r0 + tx] = (__bf16)tile[tx][ty + i*8];
    } else {
        int wv = tid >> 6, lane = tid & 63;
        int token = (idx - 8192) * 4 + wv;
        const float4* xr = (const float4*)(x + (size_t)token * D_);
        float4 xa = xr[lane*2], xb = xr[lane*2 + 1];

        bf16x8 xv = {(__bf16)xa.x,(__bf16)xa.y,(__bf16)xa.z,(__bf16)xa.w,
                     (__bf16)xb.x,(__bf16)xb.y,(__bf16)xb.z,(__bf16)xb.w};
        *(bf16x8*)(xlin + (size_t)token * D_ + lane * 8) = xv;

        const float4* vr = (const float4*)vw;
        float sv = dot8(xa, xb, vr[lane*2], vr[lane*2 + 1]);
        float sg0, sg1, sg2, sg3;
        {
            const float4* g0 = (const float4*)(gw + 0*D_);
            const float4* g1 = (const float4*)(gw + 1*D_);
            const float4* g2 = (const float4*)(gw + 2*D_);
            const float4* g3 = (const float4*)(gw + 3*D_);
            sg0 = dot8(xa, xb, g0[lane*2], g0[lane*2+1]);
            sg1 = dot8(xa, xb, g1[lane*2], g1[lane*2+1]);
            sg2 = dot8(xa, xb, g2[lane*2], g2[lane*2+1]);
            sg3 = dot8(xa, xb, g3[lane*2], g3[lane*2+1]);
        }
        sv  = wave_sum(sv);
        sg0 = wave_sum(sg0); sg1 = wave_sum(sg1);
        sg2 = wave_sum(sg2); sg3 = wave_sum(sg3);

        if (lane == 0) {
            float v = sv + vb[0];
            v = fminf(fmaxf(v, -3.0f), 3.0f);
            float eps = log1pf(expf(epsp[0])) + 1e-6f;      // softplus + 1e-6
            dbuf[token] = make_float2(v - 2.0f, -(eps + gamma[0]));

            float l0 = sg0 + gb[0], l1 = sg1 + gb[1], l2 = sg2 + gb[2], l3 = sg3 + gb[3];
            float best = l0; int be = 0;                     // first-max on tie
            if (l1 > best) { best = l1; be = 1; }
            if (l2 > best) { best = l2; be = 2; }
            if (l3 > best) { best = l3; be = 3; }
            eid[token] = be;
        }
    }
}

// ---------------------------------------------------------------------------
// Merged route + scan. Block 0 (1024 thr): atomic-free counting sort.
// Block 1: continued-fraction scan with group-of-8 register prefetch.
// ---------------------------------------------------------------------------
__global__ __launch_bounds__(1024) void route_scan_kernel(
        const int* __restrict__ eid, int* __restrict__ perm,
        int* __restrict__ cnt, int* __restrict__ tpre,
        const float2* __restrict__ dbuf, float2* __restrict__ Lb,
        float2* __restrict__ Ub, float2* __restrict__ feats) {
    int tid = threadIdx.x;
    if (blockIdx.x == 0) {
        __shared__ int chunkcnt[256][4];
        __shared__ int chunkoff[256][4];
        __shared__ int totals[4];
        int wv = tid >> 6, lane = tid & 63;

        for (int c = wv; c < 256; c += 16) {
            int e = eid[c * 64 + lane];
            unsigned long long m0 = __ballot(e == 0);
            unsigned long long m1 = __ballot(e == 1);
            unsigned long long m2 = __ballot(e == 2);
            unsigned long long m3 = __ballot(e == 3);
            if (lane == 0) {
                chunkcnt[c][0] = __popcll(m0);
                chunkcnt[c][1] = __popcll(m1);
                chunkcnt[c][2] = __popcll(m2);
                chunkcnt[c][3] = __popcll(m3);
            }
        }
        __syncthreads();

        if (wv < 4) {
            int e = wv, carry = 0;
            #pragma unroll
            for (int g = 0; g < 4; ++g) {
                int idx = g * 64 + lane;
                int v = chunkcnt[idx][e];
                int s = v;
                #pragma unroll
                for (int off = 1; off < 64; off <<= 1) {
                    int u = __shfl_up(s, off);
                    if (lane >= off) s += u;
                }
                chunkoff[idx][e] = carry + s - v;
                carry += __shfl(s, 63);
            }
            if (lane == 0) { cnt[e] = carry; totals[e] = carry; }
        }
        __syncthreads();
        if (tid == 0) {
            int acc = 0;
            #pragma unroll
            for (int e = 0; e < E_; ++e) { tpre[e] = acc; acc += (totals[e] + 255) >> 8; }
            tpre[4] = acc;
        }

        for (int c = wv; c < 256; c += 16) {
            int t = c * 64 + lane;
            int e = eid[t];
            unsigned long long m0 = __ballot(e == 0);
            unsigned long long m1 = __ballot(e == 1);
            unsigned long long m2 = __ballot(e == 2);
            unsigned long long m3 = __ballot(e == 3);
            unsigned long long mym = (e == 0) ? m0 : (e == 1) ? m1 : (e == 2) ? m2 : m3;
            unsigned long long below = lane ? (mym & ((1ull << lane) - 1ull)) : 0ull;
            int pos = chunkoff[c][e] + __popcll(below);
            perm[e * CAP_ + pos] = t;
        }
    } else {
        __shared__ alignas(16) float chunkM[8][64][8];
        __shared__ alignas(16) float bound[8][64][4];
        int s = tid >> 6, c = tid & 63;
        int b = s & 3, dir = (s >> 2) & 1;

        if (tid < 512) {
            float ar=1, ai=0, br=0, bi=0, cr=0, ci=0, dr=1, di=0;
            float2 cur[8], nxt[8];
            {
                int seq0 = c * 64;
                const float2* p = dbuf + (dir ? (b*N_ + N_ - 8 - seq0) : (b*N_ + seq0));
                load8f2(p, cur);
            }
            for (int g = 0; g < 8; ++g) {
                if (g < 7) {
                    int seq0 = c * 64 + (g + 1) * 8;
                    const float2* p = dbuf + (dir ? (b*N_ + N_ - 8 - seq0) : (b*N_ + seq0));
                    load8f2(p, nxt);
                }
                #pragma unroll
                for (int q = 0; q < 8; ++q) {
                    float2 dv = dir ? cur[7 - q] : cur[q];
                    float nar = dv.x*ar - dv.y*ai - cr;
                    float nai = dv.x*ai + dv.y*ar - ci;
                    float nbr = dv.x*br - dv.y*bi - dr;
                    float nbi = dv.x*bi + dv.y*br - di;
                    cr = ar; ci = ai; dr = br; di = bi;
                    ar = nar; ai = nai; br = nbr; bi = nbi;
                }
                float m = fmaxf(fmaxf(fmaxf(fabsf(ar),fabsf(ai)),fmaxf(fabsf(br),fabsf(bi))),
                                fmaxf(fmaxf(fabsf(cr),fabsf(ci)),fmaxf(fabsf(dr),fabsf(di))));
                float inv = 1.0f / fmaxf(m, 1e-30f);
                ar*=inv; ai*=inv; br*=inv; bi*=inv; cr*=inv; ci*=inv; dr*=inv; di*=inv;
                #pragma unroll
                for (int q = 0; q < 8; ++q) cur[q] = nxt[q];
            }
            float* cm = chunkM[s][c];
            cm[0]=ar; cm[1]=ai; cm[2]=br; cm[3]=bi; cm[4]=cr; cm[5]=ci; cm[6]=dr; cm[7]=di;
        }
        __syncthreads();

        if (tid < 8) {
            int ss = tid;
            float pr=1, pi=0, qr=0, qi=0;
            for (int cc = 0; cc < 64; ++cc) {
                float* bd = bound[ss][cc];
                bd[0]=pr; bd[1]=pi; bd[2]=qr; bd[3]=qi;
                const float* m = chunkM[ss][cc];
                float npr = m[0]*pr - m[1]*pi + m[2]*qr - m[3]*qi;
                float npi = m[0]*pi + m[1]*pr + m[2]*qi + m[3]*qr;
                float nqr = m[4]*pr - m[5]*pi + m[6]*qr - m[7]*qi;
                float nqi = m[4]*pi + m[5]*pr + m[6]*qi + m[7]*qr;
                float mx = fmaxf(fmaxf(fabsf(npr),fabsf(npi)), fmaxf(fabsf(nqr),fabsf(nqi)));
                float inv = 1.0f / fmaxf(mx, 1e-30f);
                pr = npr*inv; pi = npi*inv; qr = nqr*inv; qi = nqi*inv;
            }
        }
        __syncthreads();

        if (tid < 512) {
            const float* bd = bound[s][c];
            float pr=bd[0], pi=bd[1], qr=bd[2], qi=bd[3];
            float den = fmaxf(pr*pr + pi*pi, 1e-30f);
            float invr = (qr*pr + qi*pi) / den;
            float invi = (qi*pr - qr*pi) / den;
            float2 cur[8], nxt[8];
            {
                int seq0 = c * 64;
                const float2* p = dbuf + (dir ? (b*N_ + N_ - 8 - seq0) : (b*N_ + seq0));
                load8f2(p, cur);
            }
            for (int g = 0; g < 8; ++g) {
                if (g < 7) {
                    int seq0 = c * 64 + (g + 1) * 8;
                    const float2* p = dbuf + (dir ? (b*N_ + N_ - 8 - seq0) : (b*N_ + seq0));
                    load8f2(p, nxt);
                }
                #pragma unroll
                for (int q = 0; q < 8; ++q) {
                    int seq = c * 64 + g * 8 + q;
                    int orig = dir ? (N_ - 1 - seq) : seq;
                    int t = b * N_ + orig;
                    float2 dv = dir ? cur[7 - q] : cur[q];
                    float Lr = dv.x - invr, Li = dv.y - invi;
                    if (dir) Ub[t] = make_float2(Lr, Li);
                    else     Lb[t] = make_float2(Lr, Li);
                    float d2 = Lr*Lr + Li*Li;
                    invr = Lr / d2; invi = -Li / d2;
                }
                #pragma unroll
                for (int q = 0; q < 8; ++q) cur[q] = nxt[q];
            }
        }
        __threadfence();
        __syncthreads();

        for (int t = tid; t < T_; t += 1024) {
            float2 L = Lb[t], U = Ub[t], dv = dbuf[t];
            float sr = L.x + U.x - dv.x;
            float si = L.y + U.y - dv.y;
            float den = sr*sr + si*si;
            float Gr = sr / den, Gi = -si / den;
            Gr = fminf(fmaxf(Gr, -10.0f), 10.0f);
            Gi = fminf(fmaxf(Gi, -10.0f), 10.0f);
            feats[t] = make_float2(Gr, Gi);
        }
    }
}

// ---------------------------------------------------------------------------
// GEMM1: H = gelu(X @ w1t^T + b1), A gathered from xlin via perm.
// M=tpre[4]*256, N=2048, K=512, BK=32 (KT=16). 256x128 tile, 512 thr
// (8 waves 4Mx2N, wave 64x64). LDS 48KB FULLY double-buffered
// (A 2x16K + B 2x8K, 64B rows, no swizzle needed). One barrier per step;
// stage(kt+1) issued right after the barrier -> latency hidden under MFMA.
// ---------------------------------------------------------------------------
__global__ __launch_bounds__(512, 4) void gemm1_kernel(
        const __bf16* __restrict__ xlin, const __bf16* __restrict__ w1t,
        const float* __restrict__ b1, __bf16* __restrict__ Hb,
        const int* __restrict__ tpre, const int* __restrict__ cnt_p,
        const int* __restrict__ perm) {
    int bid = blockIdx.x;
    int lb  = (bid & 7) * 136 + (bid >> 3);     // XCD swizzle (1088 = 8*136)
    int rt = lb >> 4, ct = lb & 15;             // rt: 256-row tile
    if (rt >= tpre[4]) return;
    int e = 0;
    #pragma unroll
    for (int k = 1; k < E_; ++k) if (rt >= tpre[k]) e = k;
    int cnt = cnt_p[e];
    int base = tpre[e] * 256;

    __shared__ __bf16 A[2][256 * 32];   // 2 x 16KB, 64B rows
    __shared__ __bf16 Bm[2][128 * 32];  // 2 x 8KB

    int tid = threadIdx.x, lane = tid & 63, wv = tid >> 6;
    int fl = lane & 15, gl = lane >> 4;
    int wr = wv >> 1, wc = wv & 1;      // 4M x 2N

    // --- staging geometry: thread t -> row t>>2 (+128 for i=1), slot t&3 ---
    int srow = tid >> 2;                 // 0..127
    int selc = (tid & 3) * 8;            // element offset within 32-col row
    // A: 2 gathered token rows per thread (K-invariant lookups).
    const __bf16* aS[2];
    #pragma unroll
    for (int i = 0; i < 2; ++i) {
        int gr = rt * 256 + srow + i * 128;          // padded global row
        int il = gr - base;
        int token = (il < cnt) ? perm[e * CAP_ + il] : 0;
        aS[i] = xlin + (size_t)token * D_ + selc;
    }
    const __bf16* bS0 = w1t + (size_t)(e * F_ + ct * 128 + srow) * 512 + selc;
    // dest: linear (wave-uniform base + lane*16B, verified: w*512 + l*8 el)
    lbf16* aD[2] = { (lbf16*)A[0] + wv * 512, (lbf16*)A[1] + wv * 512 };
    lbf16* bD[2] = { (lbf16*)Bm[0] + wv * 512, (lbf16*)Bm[1] + wv * 512 };

    // --- read geometry: 64B rows, plain (banks auto-balanced) ---
    int gl16 = gl * 16;
    const char* Ab[2] = { (const char*)A[0]  + (wr * 64 + fl) * 64,
                          (const char*)A[1]  + (wr * 64 + fl) * 64 };
    const char* Bb[2] = { (const char*)Bm[0] + (wc * 64 + fl) * 64,
                          (const char*)Bm[1] + (wc * 64 + fl) * 64 };

    f32x4 acc[4][4];
    #pragma unroll
    for (int m = 0; m < 4; ++m)
        #pragma unroll
        for (int n = 0; n < 4; ++n) acc[m][n] = (f32x4){0.f,0.f,0.f,0.f};

    // prologue: stage(0) -> buf0 (3 loads/thread)
    gload_lds16(aS[0], aD[0]);
    gload_lds16(aS[1], aD[0] + 4096);
    gload_lds16(bS0, bD[0]);

    #pragma unroll
    for (int kt = 0; kt < 16; ++kt) {
        int cur = kt & 1, nxt = cur ^ 1;
        VM0_BARRIER();                       // stage(kt) landed everywhere
        __builtin_amdgcn_sched_barrier(0);
        if (kt + 1 < 16) {                   // stage(kt+1): full step to land
            gload_lds16(aS[0] + (kt + 1) * 32, aD[nxt]);
            gload_lds16(aS[1] + (kt + 1) * 32, aD[nxt] + 4096);
            gload_lds16(bS0 + (kt + 1) * 32, bD[nxt]);
        }
        mfma_step32(Ab[cur], Bb[cur], gl16, acc);
        // no trailing barrier: buf[cur] is overwritten by stage(kt+2),
        // issued after the kt+1 top barrier; every wave reaching that
        // barrier has completed its buf[cur] ds_reads (MFMA consumed them).
    }

    int gre = rt * 256 + wr * 64;
    int gce = ct * 128 + wc * 64;
    float b1v[4];
    #pragma unroll
    for (int n = 0; n < 4; ++n) b1v[n] = b1[e * F_ + gce + n*16 + fl];
    #pragma unroll
    for (int m = 0; m < 4; ++m)
        #pragma unroll
        for (int r = 0; r < 4; ++r) {
            __bf16* hrow = Hb + (size_t)(gre + m*16 + gl*4 + r) * F_ + gce;
            #pragma unroll
            for (int n = 0; n < 4; ++n)
                hrow[n*16 + fl] = (__bf16)fast_gelu(acc[m][n][r] + b1v[n]);
        }
}

// ---------------------------------------------------------------------------
// GEMM2: out[token] = H @ w2t^T + b2 + bk*spec.  N=512, K=2048 (KT=32).
// Proven R16 config: 256x128 tile, 48KB single-buffer, 2-barrier loop.
// ---------------------------------------------------------------------------
__global__ __launch_bounds__(512, 4) void gemm2_kernel(
        const __bf16* __restrict__ Hb, const __bf16* __restrict__ w2t,
        const float* __restrict__ b2, const float* __restrict__ outw,
        const float* __restrict__ outb, const float* __restrict__ bk,
        const float2* __restrict__ feats, const int* __restrict__ perm,
        const int* __restrict__ cnt_p, const int* __restrict__ tpre,
        float* __restrict__ out) {
    int bid = blockIdx.x;
    int lb  = (bid & 7) * 34 + (bid >> 3);      // XCD swizzle (272 = 8*34)
    int rt = lb >> 2, ct = lb & 3;              // rt: 256-row tile
    if (rt >= tpre[4]) return;
    int e = 0;
    #pragma unroll
    for (int k = 1; k < E_; ++k) if (rt >= tpre[k]) e = k;

    __shared__ __bf16 A[256 * 64];    // 32KB
    __shared__ __bf16 Bm[128 * 64];   // 16KB

    int tid = threadIdx.x, lane = tid & 63, wv = tid >> 6;
    int fl = lane & 15, gl = lane >> 4;
    int wr = wv >> 1, wc = wv & 1;

    int r8    = lane >> 3;
    int scolb = ((lane & 7) * 16) ^ (r8 << 4);
    const __bf16* aS0 = Hb  + (size_t)(rt * 256 + wv * 32 + r8) * F_ + (scolb >> 1);
    const __bf16* bS0 = w2t + (size_t)(e * D_ + ct * 128 + wv * 16 + r8) * F_ + (scolb >> 1);
    lbf16* aD0 = (lbf16*)A  + wv * 32 * 64;
    lbf16* bD0 = (lbf16*)Bm + wv * 16 * 64;

    int xorv = (fl & 7) << 4;
    int cs0 = (gl * 16) ^ xorv;
    int cs1 = (64 + gl * 16) ^ xorv;
    const char* Ab = (const char*)A  + (wr * 64 + fl) * 128;
    const char* Bb = (const char*)Bm + (wc * 64 + fl) * 128;

    f32x4 acc[4][4];
    #pragma unroll
    for (int m = 0; m < 4; ++m)
        #pragma unroll
        for (int n = 0; n < 4; ++n) acc[m][n] = (f32x4){0.f,0.f,0.f,0.f};

    #pragma unroll
    for (int i = 0; i < 4; ++i)
        gload_lds16(aS0 + (size_t)i * 8 * F_, aD0 + i * 512);
    #pragma unroll
    for (int i = 0; i < 2; ++i)
        gload_lds16(bS0 + (size_t)i * 8 * F_, bD0 + i * 512);

    for (int kt = 0; kt < 32; ++kt) {
        __syncthreads();
        mfma_tile(Ab, Bb, cs0, cs1, acc);
        if (kt + 1 < 32) {
            LGKM_BARRIER();
            #pragma unroll
            for (int i = 0; i < 4; ++i)
                gload_lds16(aS0 + (size_t)i * 8 * F_ + (kt + 1) * 64, aD0 + i * 512);
            #pragma unroll
            for (int i = 0; i < 2; ++i)
                gload_lds16(bS0 + (size_t)i * 8 * F_ + (kt + 1) * 64, bD0 + i * 512);
        }
    }

    int cnt = cnt_p[e];
    int ibase = rt * 256 + wr * 64 - tpre[e] * 256;
    int gce = ct * 128 + wc * 64;
    float c_b2[4], c_o0[4], c_o1[4], c_ob[4], c_bk[4];
    #pragma unroll
    for (int n = 0; n < 4; ++n) {
        int dcol = gce + n*16 + fl;
        c_b2[n] = b2[e * D_ + dcol];
        c_o0[n] = outw[dcol * 2 + 0];
        c_o1[n] = outw[dcol * 2 + 1];
        c_ob[n] = outb[dcol];
        c_bk[n] = bk[dcol];
    }
    #pragma unroll
    for (int m = 0; m < 4; ++m)
        #pragma unroll
        for (int r = 0; r < 4; ++r) {
            int i = ibase + m*16 + gl*4 + r;
            if (i >= cnt) continue;
            int token = perm[e * CAP_ + i];
            float2 ft = feats[token];
            float* orow = out + (size_t)token * D_;
            #pragma unroll
            for (int n = 0; n < 4; ++n) {
                int dcol = gce + n*16 + fl;
                float spec = ft.x * c_o0[n] + ft.y * c_o1[n] + c_ob[n];
                orow[dcol] = acc[m][n][r] + c_b2[n] + c_bk[n] * spec;
            }
        }
}

// ---------------------------------------------------------------------------
extern "C" void kernel_launch(void* const* d_in, const int* in_sizes, int n_in,
                              void* d_out, int out_size, void* d_ws, size_t ws_size,
                              hipStream_t stream) {
    const float* x     = (const float*)d_in[0];
    const float* vpw   = (const float*)d_in[1];
    const float* vpb   = (const float*)d_in[2];
    const float* gamma = (const float*)d_in[3];
    const float* epsp  = (const float*)d_in[4];
    const float* gw    = (const float*)d_in[5];
    const float* gb    = (const float*)d_in[6];
    const float* w1    = (const float*)d_in[7];
    const float* b1    = (const float*)d_in[8];
    const float* w2    = (const float*)d_in[9];
    const float* b2    = (const float*)d_in[10];
    const float* ow    = (const float*)d_in[11];
    const float* ob    = (const float*)d_in[12];
    const float* bk    = (const float*)d_in[13];
    float* out = (float*)d_out;    // reference output dtype is float32

    const size_t szW  = (size_t)E_ * F_ * D_ * sizeof(__bf16);     // 8 MB each
    const size_t szF2 = (size_t)T_ * sizeof(float2);               // 128 KB each
    const size_t szPm = (size_t)E_ * CAP_ * sizeof(int);           // 256 KB
    const size_t szCt = 256;
    const size_t szXl = (size_t)T_ * D_ * sizeof(__bf16);          // 16.8 MB
    const size_t szH  = (size_t)PADROWS * F_ * sizeof(__bf16);     // 71.3 MB
    const size_t szEi = (size_t)T_ * sizeof(int);                  // 64 KB
    size_t need = 2*szW + 4*szF2 + szPm + 2*szCt + szXl + szH + szEi + 16*256;

    __bf16 *w1t, *w2t, *xlin, *Hbuf; float2 *dbuf, *Lb, *Ub, *feats;
    int *perm, *cnt, *tpre, *eid;
    int use_ws = (d_ws != nullptr && ws_size >= need);
    if (use_ws) {
        size_t off = 0;
        auto carve = [&](size_t bytes) {
            void* p = (char*)d_ws + off;
            off += (bytes + 255) & ~(size_t)255;
            return p;
        };
        w1t   = (__bf16*)carve(szW);
        w2t   = (__bf16*)carve(szW);
        xlin  = (__bf16*)carve(szXl);
        Hbuf  = (__bf16*)carve(szH);
        dbuf  = (float2*)carve(szF2);
        Lb    = (float2*)carve(szF2);
        Ub    = (float2*)carve(szF2);
        feats = (float2*)carve(szF2);
        perm  = (int*)   carve(szPm);
        cnt   = (int*)   carve(szCt);
        tpre  = (int*)   carve(szCt);
        eid   = (int*)   carve(szEi);
    } else {
        void* p;
        hipGetSymbolAddress(&p, HIP_SYMBOL(s_w1t));  w1t   = (__bf16*)p;
        hipGetSymbolAddress(&p, HIP_SYMBOL(s_w2t));  w2t   = (__bf16*)p;
        hipGetSymbolAddress(&p, HIP_SYMBOL(s_xl));   xlin  = (__bf16*)p;
        hipGetSymbolAddress(&p, HIP_SYMBOL(s_H));    Hbuf  = (__bf16*)p;
        hipGetSymbolAddress(&p, HIP_SYMBOL(s_d));    dbuf  = (float2*)p;
        hipGetSymbolAddress(&p, HIP_SYMBOL(s_L));    Lb    = (float2*)p;
        hipGetSymbolAddress(&p, HIP_SYMBOL(s_U));    Ub    = (float2*)p;
        hipGetSymbolAddress(&p, HIP_SYMBOL(s_feats));feats = (float2*)p;
        hipGetSymbolAddress(&p, HIP_SYMBOL(s_perm)); perm  = (int*)p;
        hipGetSymbolAddress(&p, HIP_SYMBOL(s_cnt));  cnt   = (int*)p;
        hipGetSymbolAddress(&p, HIP_SYMBOL(s_tpre)); tpre  = (int*)p;
        hipGetSymbolAddress(&p, HIP_SYMBOL(s_eid));  eid   = (int*)p;
    }

    prep_trans_kernel<<<12288, 256, 0, stream>>>(w1, w2, w1t, w2t,
                                                 x, vpw, vpb, gamma, epsp, gw, gb,
                                                 dbuf, eid, xlin);
    route_scan_kernel<<<2, 1024, 0, stream>>>(eid, perm, cnt, tpre, dbuf, Lb, Ub, feats);
    gemm1_kernel<<<R256*16, 512, 0, stream>>>(xlin, w1t, b1, Hbuf, tpre, cnt, perm);
    gemm2_kernel<<<R256*4, 512, 0, stream>>>(Hbuf, w2t, b2, ow, ob, bk,
                                             feats, perm, cnt, tpre, out);
}

// Round 24
// 194.650 us; speedup vs baseline: 1.0050x; 1.0050x over previous
//
#include <hip/hip_runtime.h>
#include <hip/hip_bf16.h>
#include <math.h>

// ---------------------------------------------------------------------------
// LanguageModel_66477503807731: top-1 MoE FFN + tridiagonal Green's-function
// spectral features. B=4,N=4096,D=512,E=4,F=2048. Output fp32.
// R24: restore of R22 (measured session best, 194.7us). R23 (BK=32 pipelined
// dbuf) was strike FIVE on within-block pipelining: predicted conflict-free
// 64B rows are in fact 8-way bank conflicts (bank = (fl&1)*16+gl*4 -> 8
// banks for 64 lanes; 4.39M conflicts, gemm1 90us). Final config:
//   - split grouped GEMMs, 256x128 tile, 512thr (8 waves 4Mx2N, wave 64x64),
//     48KB single-buffer LDS, gload_lds + rule-21 XOR swizzle (128B rows),
//     2-barrier K-loop, XCD swizzle on compact grids.
//   - gemm1 A gathered directly from token-linear xlin via perm (per-lane
//     gload_lds source); no reorder kernel.
//   - merged prep+transpose; ballot counting-sort routing (no atomics);
//     Mobius scan with group-of-8 register prefetch; fast_gelu epilogue.
// Session: 534us (R6 first pass) -> 194.7us. absmax 0.015625.
// ---------------------------------------------------------------------------

typedef __bf16 bf16x8 __attribute__((ext_vector_type(8)));
typedef float  f32x4  __attribute__((ext_vector_type(4)));
typedef __attribute__((address_space(3))) __bf16 lbf16;

#define B_   4
#define N_   4096
#define D_   512
#define E_   4
#define F_   2048
#define T_   (B_*N_)        // 16384 tokens
#define CAP_ T_
#define R256 68             // max 256-row tiles: 16384/256 + 4
#define PADROWS (R256*256)  // 17408

#define LGKM_BARRIER() asm volatile("s_waitcnt lgkmcnt(0)\n\ts_barrier" ::: "memory")

__device__ __forceinline__ void gload_lds16(const __bf16* g, lbf16* l) {
    __builtin_amdgcn_global_load_lds(
        (__attribute__((address_space(1))) void*)(void*)g,
        (__attribute__((address_space(3))) void*)l, 16, 0, 0);
}

__device__ __forceinline__ float fast_gelu(float x) {
    float u = 1.5957691216f * fmaf(0.044715f * x, x * x, x);
    return x / (1.0f + __expf(-u));
}

// Load 8 consecutive float2 (16B-aligned base) as 4x float4.
__device__ __forceinline__ void load8f2(const float2* p, float2* dst) {
    const float4* q = (const float4*)p;
    #pragma unroll
    for (int i = 0; i < 4; ++i) {
        float4 t = q[i];
        dst[2*i]   = make_float2(t.x, t.y);
        dst[2*i+1] = make_float2(t.z, t.w);
    }
}

// One BK=64 MFMA phase for a 64x64 wave tile: 16 ds_read_b128 + 32 MFMA.
__device__ __forceinline__ void mfma_tile(const char* Ab, const char* Bb,
                                          int cs0, int cs1, f32x4 acc[4][4]) {
    #pragma unroll
    for (int ks = 0; ks < 2; ++ks) {
        int cs = ks ? cs1 : cs0;
        bf16x8 af[4], bfr[4];
        #pragma unroll
        for (int m = 0; m < 4; ++m)
            af[m] = *(const bf16x8*)(Ab + m * 2048 + cs);
        #pragma unroll
        for (int n = 0; n < 4; ++n)
            bfr[n] = *(const bf16x8*)(Bb + n * 2048 + cs);
        #pragma unroll
        for (int m = 0; m < 4; ++m)
            #pragma unroll
            for (int n = 0; n < 4; ++n)
                acc[m][n] = __builtin_amdgcn_mfma_f32_16x16x32_bf16(af[m], bfr[n], acc[m][n], 0, 0, 0);
    }
}

// Fallback-only static scratch (used iff ws_size too small; ws observed 256MB).
__device__ alignas(256) __bf16 s_w1t[(size_t)E_*F_*D_];
__device__ alignas(256) __bf16 s_w2t[(size_t)E_*D_*F_];
__device__ alignas(256) __bf16 s_xl[(size_t)T_*D_];
__device__ alignas(256) __bf16 s_H[(size_t)PADROWS*F_];
__device__ alignas(256) float2 s_d[T_];
__device__ alignas(256) float2 s_feats[T_];
__device__ alignas(256) float2 s_L[T_];
__device__ alignas(256) float2 s_U[T_];
__device__ alignas(256) int    s_perm[E_*CAP_];
__device__ alignas(256) int    s_cnt[E_];
__device__ alignas(256) int    s_tpre[8];
__device__ alignas(256) int    s_eid[T_];

__device__ inline float dot8(float4 a, float4 b, float4 c, float4 d) {
    float s =      a.x * c.x;
    s = fmaf(a.y, c.y, s); s = fmaf(a.z, c.z, s); s = fmaf(a.w, c.w, s);
    s = fmaf(b.x, d.x, s); s = fmaf(b.y, d.y, s); s = fmaf(b.z, d.z, s);
    s = fmaf(b.w, d.w, s);
    return s;
}

__device__ inline float wave_sum(float s) {
    #pragma unroll
    for (int off = 32; off > 0; off >>= 1) s += __shfl_xor(s, off);
    return s;
}

// ---------------------------------------------------------------------------
// Merged: weight transposes (blocks [0,8192)) + prep (blocks [8192,12288)).
// Prep also writes xlin[token][512] bf16 (token-linear activation).
// ---------------------------------------------------------------------------
__global__ __launch_bounds__(256) void prep_trans_kernel(
        const float* __restrict__ w1, const float* __restrict__ w2,
        __bf16* __restrict__ w1t, __bf16* __restrict__ w2t,
        const float* __restrict__ x,
        const float* __restrict__ vw, const float* __restrict__ vb,
        const float* __restrict__ gamma, const float* __restrict__ epsp,
        const float* __restrict__ gw, const float* __restrict__ gb,
        float2* __restrict__ dbuf, int* __restrict__ eid,
        __bf16* __restrict__ xlin) {
    __shared__ alignas(16) float tile[32][33];
    int idx = blockIdx.x;
    int tid = threadIdx.x;
    if (idx < 8192) {
        int which = idx >> 12;            // 0: w1, 1: w2
        int r = idx & 4095;
        int e = r >> 10;
        int t = r & 1023;
        int R, C, c0, r0;
        const float* s;
        __bf16* d;
        if (which == 0) { R = D_; C = F_; c0 = (t & 63) * 32; r0 = (t >> 6) * 32;
                          s = w1 + (size_t)e * R * C; d = w1t + (size_t)e * R * C; }
        else            { R = F_; C = D_; c0 = (t & 15) * 32; r0 = (t >> 4) * 32;
                          s = w2 + (size_t)e * R * C; d = w2t + (size_t)e * R * C; }
        int tx = tid & 31, ty = tid >> 5;
        #pragma unroll
        for (int i = 0; i < 4; ++i)
            tile[ty + i*8][tx] = s[(size_t)(r0 + ty + i*8) * C + c0 + tx];
        __syncthreads();
        #pragma unroll
        for (int i = 0; i < 4; ++i)
            d[(size_t)(c0 + ty + i*8) * R + r0 + tx] = (__bf16)tile[tx][ty + i*8];
    } else {
        int wv = tid >> 6, lane = tid & 63;
        int token = (idx - 8192) * 4 + wv;
        const float4* xr = (const float4*)(x + (size_t)token * D_);
        float4 xa = xr[lane*2], xb = xr[lane*2 + 1];

        // token-linear bf16 copy (free: values already in registers)
        bf16x8 xv = {(__bf16)xa.x,(__bf16)xa.y,(__bf16)xa.z,(__bf16)xa.w,
                     (__bf16)xb.x,(__bf16)xb.y,(__bf16)xb.z,(__bf16)xb.w};
        *(bf16x8*)(xlin + (size_t)token * D_ + lane * 8) = xv;

        const float4* vr = (const float4*)vw;
        float sv = dot8(xa, xb, vr[lane*2], vr[lane*2 + 1]);
        float sg0, sg1, sg2, sg3;
        {
            const float4* g0 = (const float4*)(gw + 0*D_);
            const float4* g1 = (const float4*)(gw + 1*D_);
            const float4* g2 = (const float4*)(gw + 2*D_);
            const float4* g3 = (const float4*)(gw + 3*D_);
            sg0 = dot8(xa, xb, g0[lane*2], g0[lane*2+1]);
            sg1 = dot8(xa, xb, g1[lane*2], g1[lane*2+1]);
            sg2 = dot8(xa, xb, g2[lane*2], g2[lane*2+1]);
            sg3 = dot8(xa, xb, g3[lane*2], g3[lane*2+1]);
        }
        sv  = wave_sum(sv);
        sg0 = wave_sum(sg0); sg1 = wave_sum(sg1);
        sg2 = wave_sum(sg2); sg3 = wave_sum(sg3);

        if (lane == 0) {
            float v = sv + vb[0];
            v = fminf(fmaxf(v, -3.0f), 3.0f);
            float eps = log1pf(expf(epsp[0])) + 1e-6f;      // softplus + 1e-6
            dbuf[token] = make_float2(v - 2.0f, -(eps + gamma[0]));

            float l0 = sg0 + gb[0], l1 = sg1 + gb[1], l2 = sg2 + gb[2], l3 = sg3 + gb[3];
            float best = l0; int be = 0;                     // first-max on tie
            if (l1 > best) { best = l1; be = 1; }
            if (l2 > best) { best = l2; be = 2; }
            if (l3 > best) { best = l3; be = 3; }
            eid[token] = be;
        }
    }
}

// ---------------------------------------------------------------------------
// Merged route + scan. Block 0 (1024 thr): atomic-free counting sort.
// Block 1: continued-fraction scan with group-of-8 register prefetch.
// ---------------------------------------------------------------------------
__global__ __launch_bounds__(1024) void route_scan_kernel(
        const int* __restrict__ eid, int* __restrict__ perm,
        int* __restrict__ cnt, int* __restrict__ tpre,
        const float2* __restrict__ dbuf, float2* __restrict__ Lb,
        float2* __restrict__ Ub, float2* __restrict__ feats) {
    int tid = threadIdx.x;
    if (blockIdx.x == 0) {
        __shared__ int chunkcnt[256][4];
        __shared__ int chunkoff[256][4];
        __shared__ int totals[4];
        int wv = tid >> 6, lane = tid & 63;

        for (int c = wv; c < 256; c += 16) {
            int e = eid[c * 64 + lane];
            unsigned long long m0 = __ballot(e == 0);
            unsigned long long m1 = __ballot(e == 1);
            unsigned long long m2 = __ballot(e == 2);
            unsigned long long m3 = __ballot(e == 3);
            if (lane == 0) {
                chunkcnt[c][0] = __popcll(m0);
                chunkcnt[c][1] = __popcll(m1);
                chunkcnt[c][2] = __popcll(m2);
                chunkcnt[c][3] = __popcll(m3);
            }
        }
        __syncthreads();

        if (wv < 4) {
            int e = wv, carry = 0;
            #pragma unroll
            for (int g = 0; g < 4; ++g) {
                int idx = g * 64 + lane;
                int v = chunkcnt[idx][e];
                int s = v;
                #pragma unroll
                for (int off = 1; off < 64; off <<= 1) {
                    int u = __shfl_up(s, off);
                    if (lane >= off) s += u;
                }
                chunkoff[idx][e] = carry + s - v;
                carry += __shfl(s, 63);
            }
            if (lane == 0) { cnt[e] = carry; totals[e] = carry; }
        }
        __syncthreads();
        if (tid == 0) {
            int acc = 0;
            #pragma unroll
            for (int e = 0; e < E_; ++e) { tpre[e] = acc; acc += (totals[e] + 255) >> 8; }
            tpre[4] = acc;
        }

        for (int c = wv; c < 256; c += 16) {
            int t = c * 64 + lane;
            int e = eid[t];
            unsigned long long m0 = __ballot(e == 0);
            unsigned long long m1 = __ballot(e == 1);
            unsigned long long m2 = __ballot(e == 2);
            unsigned long long m3 = __ballot(e == 3);
            unsigned long long mym = (e == 0) ? m0 : (e == 1) ? m1 : (e == 2) ? m2 : m3;
            unsigned long long below = lane ? (mym & ((1ull << lane) - 1ull)) : 0ull;
            int pos = chunkoff[c][e] + __popcll(below);
            perm[e * CAP_ + pos] = t;
        }
    } else {
        __shared__ alignas(16) float chunkM[8][64][8];
        __shared__ alignas(16) float bound[8][64][4];
        int s = tid >> 6, c = tid & 63;
        int b = s & 3, dir = (s >> 2) & 1;

        if (tid < 512) {
            float ar=1, ai=0, br=0, bi=0, cr=0, ci=0, dr=1, di=0;
            float2 cur[8], nxt[8];
            {
                int seq0 = c * 64;
                const float2* p = dbuf + (dir ? (b*N_ + N_ - 8 - seq0) : (b*N_ + seq0));
                load8f2(p, cur);
            }
            for (int g = 0; g < 8; ++g) {
                if (g < 7) {
                    int seq0 = c * 64 + (g + 1) * 8;
                    const float2* p = dbuf + (dir ? (b*N_ + N_ - 8 - seq0) : (b*N_ + seq0));
                    load8f2(p, nxt);
                }
                #pragma unroll
                for (int q = 0; q < 8; ++q) {
                    float2 dv = dir ? cur[7 - q] : cur[q];
                    float nar = dv.x*ar - dv.y*ai - cr;
                    float nai = dv.x*ai + dv.y*ar - ci;
                    float nbr = dv.x*br - dv.y*bi - dr;
                    float nbi = dv.x*bi + dv.y*br - di;
                    cr = ar; ci = ai; dr = br; di = bi;
                    ar = nar; ai = nai; br = nbr; bi = nbi;
                }
                float m = fmaxf(fmaxf(fmaxf(fabsf(ar),fabsf(ai)),fmaxf(fabsf(br),fabsf(bi))),
                                fmaxf(fmaxf(fabsf(cr),fabsf(ci)),fmaxf(fabsf(dr),fabsf(di))));
                float inv = 1.0f / fmaxf(m, 1e-30f);
                ar*=inv; ai*=inv; br*=inv; bi*=inv; cr*=inv; ci*=inv; dr*=inv; di*=inv;
                #pragma unroll
                for (int q = 0; q < 8; ++q) cur[q] = nxt[q];
            }
            float* cm = chunkM[s][c];
            cm[0]=ar; cm[1]=ai; cm[2]=br; cm[3]=bi; cm[4]=cr; cm[5]=ci; cm[6]=dr; cm[7]=di;
        }
        __syncthreads();

        if (tid < 8) {
            int ss = tid;
            float pr=1, pi=0, qr=0, qi=0;
            for (int cc = 0; cc < 64; ++cc) {
                float* bd = bound[ss][cc];
                bd[0]=pr; bd[1]=pi; bd[2]=qr; bd[3]=qi;
                const float* m = chunkM[ss][cc];
                float npr = m[0]*pr - m[1]*pi + m[2]*qr - m[3]*qi;
                float npi = m[0]*pi + m[1]*pr + m[2]*qi + m[3]*qr;
                float nqr = m[4]*pr - m[5]*pi + m[6]*qr - m[7]*qi;
                float nqi = m[4]*pi + m[5]*pr + m[6]*qi + m[7]*qr;
                float mx = fmaxf(fmaxf(fabsf(npr),fabsf(npi)), fmaxf(fabsf(nqr),fabsf(nqi)));
                float inv = 1.0f / fmaxf(mx, 1e-30f);
                pr = npr*inv; pi = npi*inv; qr = nqr*inv; qi = nqi*inv;
            }
        }
        __syncthreads();

        if (tid < 512) {
            const float* bd = bound[s][c];
            float pr=bd[0], pi=bd[1], qr=bd[2], qi=bd[3];
            float den = fmaxf(pr*pr + pi*pi, 1e-30f);
            float invr = (qr*pr + qi*pi) / den;
            float invi = (qi*pr - qr*pi) / den;
            float2 cur[8], nxt[8];
            {
                int seq0 = c * 64;
                const float2* p = dbuf + (dir ? (b*N_ + N_ - 8 - seq0) : (b*N_ + seq0));
                load8f2(p, cur);
            }
            for (int g = 0; g < 8; ++g) {
                if (g < 7) {
                    int seq0 = c * 64 + (g + 1) * 8;
                    const float2* p = dbuf + (dir ? (b*N_ + N_ - 8 - seq0) : (b*N_ + seq0));
                    load8f2(p, nxt);
                }
                #pragma unroll
                for (int q = 0; q < 8; ++q) {
                    int seq = c * 64 + g * 8 + q;
                    int orig = dir ? (N_ - 1 - seq) : seq;
                    int t = b * N_ + orig;
                    float2 dv = dir ? cur[7 - q] : cur[q];
                    float Lr = dv.x - invr, Li = dv.y - invi;
                    if (dir) Ub[t] = make_float2(Lr, Li);
                    else     Lb[t] = make_float2(Lr, Li);
                    float d2 = Lr*Lr + Li*Li;
                    invr = Lr / d2; invi = -Li / d2;
                }
                #pragma unroll
                for (int q = 0; q < 8; ++q) cur[q] = nxt[q];
            }
        }
        __threadfence();
        __syncthreads();

        for (int t = tid; t < T_; t += 1024) {
            float2 L = Lb[t], U = Ub[t], dv = dbuf[t];
            float sr = L.x + U.x - dv.x;
            float si = L.y + U.y - dv.y;
            float den = sr*sr + si*si;
            float Gr = sr / den, Gi = -si / den;
            Gr = fminf(fmaxf(Gr, -10.0f), 10.0f);
            Gi = fminf(fmaxf(Gi, -10.0f), 10.0f);
            feats[t] = make_float2(Gr, Gi);
        }
    }
}

// ---------------------------------------------------------------------------
// GEMM1: H = gelu(X @ w1t^T + b1), A gathered directly from xlin via perm.
// M=tpre[4]*256, N=2048, K=512 (KT=8). 256x128 tile, 512 thr (8 waves
// 4Mx2N, wave 64x64), 48KB single-buffer, gload_lds (per-lane gathered
// source) + rule-21 swizzle, 2-barrier loop.
// ---------------------------------------------------------------------------
__global__ __launch_bounds__(512, 4) void gemm1_kernel(
        const __bf16* __restrict__ xlin, const __bf16* __restrict__ w1t,
        const float* __restrict__ b1, __bf16* __restrict__ Hb,
        const int* __restrict__ tpre, const int* __restrict__ cnt_p,
        const int* __restrict__ perm) {
    int bid = blockIdx.x;
    int lb  = (bid & 7) * 136 + (bid >> 3);     // XCD swizzle (1088 = 8*136)
    int rt = lb >> 4, ct = lb & 15;             // rt: 256-row tile
    if (rt >= tpre[4]) return;
    int e = 0;
    #pragma unroll
    for (int k = 1; k < E_; ++k) if (rt >= tpre[k]) e = k;
    int cnt = cnt_p[e];
    int base = tpre[e] * 256;

    __shared__ __bf16 A[256 * 64];    // 32KB, linear 128B rows
    __shared__ __bf16 Bm[128 * 64];   // 16KB

    int tid = threadIdx.x, lane = tid & 63, wv = tid >> 6;
    int fl = lane & 15, gl = lane >> 4;
    int wr = wv >> 1, wc = wv & 1;    // 4M x 2N

    int r8    = lane >> 3;
    int scolb = ((lane & 7) * 16) ^ (r8 << 4);  // pre-swizzled source col
    // Gather: 4 fixed token rows per staging thread (K-invariant).
    const __bf16* aS[4];
    #pragma unroll
    for (int i = 0; i < 4; ++i) {
        int gr = rt * 256 + wv * 32 + r8 + i * 8;   // padded global row
        int il = gr - base;                          // index within expert
        int token = (il < cnt) ? perm[e * CAP_ + il] : 0;   // pad -> row 0
        aS[i] = xlin + (size_t)token * D_ + (scolb >> 1);
    }
    const __bf16* bS0 = w1t + (size_t)(e * F_ + ct * 128 + wv * 16 + r8) * 512 + (scolb >> 1);
    lbf16* aD0 = (lbf16*)A  + wv * 32 * 64;
    lbf16* bD0 = (lbf16*)Bm + wv * 16 * 64;

    int xorv = (fl & 7) << 4;
    int cs0 = (gl * 16) ^ xorv;
    int cs1 = (64 + gl * 16) ^ xorv;
    const char* Ab = (const char*)A  + (wr * 64 + fl) * 128;
    const char* Bb = (const char*)Bm + (wc * 64 + fl) * 128;

    f32x4 acc[4][4];
    #pragma unroll
    for (int m = 0; m < 4; ++m)
        #pragma unroll
        for (int n = 0; n < 4; ++n) acc[m][n] = (f32x4){0.f,0.f,0.f,0.f};

    #pragma unroll
    for (int i = 0; i < 4; ++i)
        gload_lds16(aS[i], aD0 + i * 512);
    #pragma unroll
    for (int i = 0; i < 2; ++i)
        gload_lds16(bS0 + (size_t)i * 8 * 512, bD0 + i * 512);

    for (int kt = 0; kt < 8; ++kt) {
        __syncthreads();                       // vmcnt drain: tile visible
        mfma_tile(Ab, Bb, cs0, cs1, acc);
        if (kt + 1 < 8) {
            LGKM_BARRIER();                    // reads done before overwrite
            #pragma unroll
            for (int i = 0; i < 4; ++i)
                gload_lds16(aS[i] + (kt + 1) * 64, aD0 + i * 512);
            #pragma unroll
            for (int i = 0; i < 2; ++i)
                gload_lds16(bS0 + (size_t)i * 8 * 512 + (kt + 1) * 64, bD0 + i * 512);
        }
    }

    int gre = rt * 256 + wr * 64;
    int gce = ct * 128 + wc * 64;
    float b1v[4];
    #pragma unroll
    for (int n = 0; n < 4; ++n) b1v[n] = b1[e * F_ + gce + n*16 + fl];
    #pragma unroll
    for (int m = 0; m < 4; ++m)
        #pragma unroll
        for (int r = 0; r < 4; ++r) {
            __bf16* hrow = Hb + (size_t)(gre + m*16 + gl*4 + r) * F_ + gce;
            #pragma unroll
            for (int n = 0; n < 4; ++n)
                hrow[n*16 + fl] = (__bf16)fast_gelu(acc[m][n][r] + b1v[n]);
        }
}

// ---------------------------------------------------------------------------
// GEMM2: out[token] = H @ w2t^T + b2 + bk*spec.  N=512, K=2048 (KT=32).
// Proven R16 config: 256x128 tile, 48KB single-buffer, 2-barrier loop.
// ---------------------------------------------------------------------------
__global__ __launch_bounds__(512, 4) void gemm2_kernel(
        const __bf16* __restrict__ Hb, const __bf16* __restrict__ w2t,
        const float* __restrict__ b2, const float* __restrict__ outw,
        const float* __restrict__ outb, const float* __restrict__ bk,
        const float2* __restrict__ feats, const int* __restrict__ perm,
        const int* __restrict__ cnt_p, const int* __restrict__ tpre,
        float* __restrict__ out) {
    int bid = blockIdx.x;
    int lb  = (bid & 7) * 34 + (bid >> 3);      // XCD swizzle (272 = 8*34)
    int rt = lb >> 2, ct = lb & 3;              // rt: 256-row tile
    if (rt >= tpre[4]) return;
    int e = 0;
    #pragma unroll
    for (int k = 1; k < E_; ++k) if (rt >= tpre[k]) e = k;

    __shared__ __bf16 A[256 * 64];    // 32KB
    __shared__ __bf16 Bm[128 * 64];   // 16KB

    int tid = threadIdx.x, lane = tid & 63, wv = tid >> 6;
    int fl = lane & 15, gl = lane >> 4;
    int wr = wv >> 1, wc = wv & 1;

    int r8    = lane >> 3;
    int scolb = ((lane & 7) * 16) ^ (r8 << 4);
    const __bf16* aS0 = Hb  + (size_t)(rt * 256 + wv * 32 + r8) * F_ + (scolb >> 1);
    const __bf16* bS0 = w2t + (size_t)(e * D_ + ct * 128 + wv * 16 + r8) * F_ + (scolb >> 1);
    lbf16* aD0 = (lbf16*)A  + wv * 32 * 64;
    lbf16* bD0 = (lbf16*)Bm + wv * 16 * 64;

    int xorv = (fl & 7) << 4;
    int cs0 = (gl * 16) ^ xorv;
    int cs1 = (64 + gl * 16) ^ xorv;
    const char* Ab = (const char*)A  + (wr * 64 + fl) * 128;
    const char* Bb = (const char*)Bm + (wc * 64 + fl) * 128;

    f32x4 acc[4][4];
    #pragma unroll
    for (int m = 0; m < 4; ++m)
        #pragma unroll
        for (int n = 0; n < 4; ++n) acc[m][n] = (f32x4){0.f,0.f,0.f,0.f};

    #pragma unroll
    for (int i = 0; i < 4; ++i)
        gload_lds16(aS0 + (size_t)i * 8 * F_, aD0 + i * 512);
    #pragma unroll
    for (int i = 0; i < 2; ++i)
        gload_lds16(bS0 + (size_t)i * 8 * F_, bD0 + i * 512);

    for (int kt = 0; kt < 32; ++kt) {
        __syncthreads();
        mfma_tile(Ab, Bb, cs0, cs1, acc);
        if (kt + 1 < 32) {
            LGKM_BARRIER();
            #pragma unroll
            for (int i = 0; i < 4; ++i)
                gload_lds16(aS0 + (size_t)i * 8 * F_ + (kt + 1) * 64, aD0 + i * 512);
            #pragma unroll
            for (int i = 0; i < 2; ++i)
                gload_lds16(bS0 + (size_t)i * 8 * F_ + (kt + 1) * 64, bD0 + i * 512);
        }
    }

    int cnt = cnt_p[e];
    int ibase = rt * 256 + wr * 64 - tpre[e] * 256;
    int gce = ct * 128 + wc * 64;
    float c_b2[4], c_o0[4], c_o1[4], c_ob[4], c_bk[4];
    #pragma unroll
    for (int n = 0; n < 4; ++n) {
        int dcol = gce + n*16 + fl;
        c_b2[n] = b2[e * D_ + dcol];
        c_o0[n] = outw[dcol * 2 + 0];
        c_o1[n] = outw[dcol * 2 + 1];
        c_ob[n] = outb[dcol];
        c_bk[n] = bk[dcol];
    }
    #pragma unroll
    for (int m = 0; m < 4; ++m)
        #pragma unroll
        for (int r = 0; r < 4; ++r) {
            int i = ibase + m*16 + gl*4 + r;
            if (i >= cnt) continue;
            int token = perm[e * CAP_ + i];
            float2 ft = feats[token];
            float* orow = out + (size_t)token * D_;
            #pragma unroll
            for (int n = 0; n < 4; ++n) {
                int dcol = gce + n*16 + fl;
                float spec = ft.x * c_o0[n] + ft.y * c_o1[n] + c_ob[n];
                orow[dcol] = acc[m][n][r] + c_b2[n] + c_bk[n] * spec;
            }
        }
}

// ---------------------------------------------------------------------------
extern "C" void kernel_launch(void* const* d_in, const int* in_sizes, int n_in,
                              void* d_out, int out_size, void* d_ws, size_t ws_size,
                              hipStream_t stream) {
    const float* x     = (const float*)d_in[0];
    const float* vpw   = (const float*)d_in[1];
    const float* vpb   = (const float*)d_in[2];
    const float* gamma = (const float*)d_in[3];
    const float* epsp  = (const float*)d_in[4];
    const float* gw    = (const float*)d_in[5];
    const float* gb    = (const float*)d_in[6];
    const float* w1    = (const float*)d_in[7];
    const float* b1    = (const float*)d_in[8];
    const float* w2    = (const float*)d_in[9];
    const float* b2    = (const float*)d_in[10];
    const float* ow    = (const float*)d_in[11];
    const float* ob    = (const float*)d_in[12];
    const float* bk    = (const float*)d_in[13];
    float* out = (float*)d_out;    // reference output dtype is float32

    const size_t szW  = (size_t)E_ * F_ * D_ * sizeof(__bf16);     // 8 MB each
    const size_t szF2 = (size_t)T_ * sizeof(float2);               // 128 KB each
    const size_t szPm = (size_t)E_ * CAP_ * sizeof(int);           // 256 KB
    const size_t szCt = 256;
    const size_t szXl = (size_t)T_ * D_ * sizeof(__bf16);          // 16.8 MB
    const size_t szH  = (size_t)PADROWS * F_ * sizeof(__bf16);     // 71.3 MB
    const size_t szEi = (size_t)T_ * sizeof(int);                  // 64 KB
    size_t need = 2*szW + 4*szF2 + szPm + 2*szCt + szXl + szH + szEi + 16*256;

    __bf16 *w1t, *w2t, *xlin, *Hbuf; float2 *dbuf, *Lb, *Ub, *feats;
    int *perm, *cnt, *tpre, *eid;
    int use_ws = (d_ws != nullptr && ws_size >= need);
    if (use_ws) {
        size_t off = 0;
        auto carve = [&](size_t bytes) {
            void* p = (char*)d_ws + off;
            off += (bytes + 255) & ~(size_t)255;
            return p;
        };
        w1t   = (__bf16*)carve(szW);
        w2t   = (__bf16*)carve(szW);
        xlin  = (__bf16*)carve(szXl);
        Hbuf  = (__bf16*)carve(szH);
        dbuf  = (float2*)carve(szF2);
        Lb    = (float2*)carve(szF2);
        Ub    = (float2*)carve(szF2);
        feats = (float2*)carve(szF2);
        perm  = (int*)   carve(szPm);
        cnt   = (int*)   carve(szCt);
        tpre  = (int*)   carve(szCt);
        eid   = (int*)   carve(szEi);
    } else {
        void* p;
        hipGetSymbolAddress(&p, HIP_SYMBOL(s_w1t));  w1t   = (__bf16*)p;
        hipGetSymbolAddress(&p, HIP_SYMBOL(s_w2t));  w2t   = (__bf16*)p;
        hipGetSymbolAddress(&p, HIP_SYMBOL(s_xl));   xlin  = (__bf16*)p;
        hipGetSymbolAddress(&p, HIP_SYMBOL(s_H));    Hbuf  = (__bf16*)p;
        hipGetSymbolAddress(&p, HIP_SYMBOL(s_d));    dbuf  = (float2*)p;
        hipGetSymbolAddress(&p, HIP_SYMBOL(s_L));    Lb    = (float2*)p;
        hipGetSymbolAddress(&p, HIP_SYMBOL(s_U));    Ub    = (float2*)p;
        hipGetSymbolAddress(&p, HIP_SYMBOL(s_feats));feats = (float2*)p;
        hipGetSymbolAddress(&p, HIP_SYMBOL(s_perm)); perm  = (int*)p;
        hipGetSymbolAddress(&p, HIP_SYMBOL(s_cnt));  cnt   = (int*)p;
        hipGetSymbolAddress(&p, HIP_SYMBOL(s_tpre)); tpre  = (int*)p;
        hipGetSymbolAddress(&p, HIP_SYMBOL(s_eid));  eid   = (int*)p;
    }

    prep_trans_kernel<<<12288, 256, 0, stream>>>(w1, w2, w1t, w2t,
                                                 x, vpw, vpb, gamma, epsp, gw, gb,
                                                 dbuf, eid, xlin);
    route_scan_kernel<<<2, 1024, 0, stream>>>(eid, perm, cnt, tpre, dbuf, Lb, Ub, feats);
    gemm1_kernel<<<R256*16, 512, 0, stream>>>(xlin, w1t, b1, Hbuf, tpre, cnt, perm);
    gemm2_kernel<<<R256*4, 512, 0, stream>>>(Hbuf, w2t, b2, ow, ob, bk,
                                             feats, perm, cnt, tpre, out);
}